// Round 2
// baseline (458.734 us; speedup 1.0000x reference)
//
#include <hip/hip_runtime.h>
#include <stdint.h>

// SelfAttentionV3: out = softmax(mask(QK^T/32)) V with Q=Xq Wq+bq etc.
// B=8, S=2048, D=1024. All GEMMs bf16 MFMA (fp32 accum), 2-phase pipelined.
//
// ws layout (bytes):
//   [0,    32M)  q_bf16  [16384][1024]
//   [32M,  64M)  k_bf16  [16384][1024]
//   [64M,  96M)  vT_bf16 [8][1024][2048]
//   [96M, 192M)  A_bf16 converted inputs (dead after projections)
//   [192M,198M)  WT_bf16 transposed weights (dead after projections)
//   [96M, 163M)  scores/P bf16 [8][2048][2048] (overlays A region)

typedef unsigned short u16;
typedef __attribute__((ext_vector_type(8))) short short8;
typedef __attribute__((ext_vector_type(4))) float f32x4;

#define BM 128
#define BN 128
#define BK 32
#define BMBK (BM * BK)

__device__ __forceinline__ u16 f2bf(float x) {
  unsigned u = __float_as_uint(x);
  return (u16)((u + 0x7FFFu + ((u >> 16) & 1u)) >> 16);  // RNE
}
__device__ __forceinline__ float bf2f(u16 h) {
  return __uint_as_float(((unsigned)h) << 16);
}

__device__ __forceinline__ void stage16(const void* g, void* l) {
  const __attribute__((address_space(1))) uint32_t* gp =
      (const __attribute__((address_space(1))) uint32_t*)(uintptr_t)g;
  __attribute__((address_space(3))) uint32_t* lp =
      (__attribute__((address_space(3))) uint32_t*)(uintptr_t)l;
  __builtin_amdgcn_global_load_lds(gp, lp, 16, 0, 0);
}

// fp32 -> bf16 elementwise convert (vectorized)
__global__ __launch_bounds__(256) void cvt(const float4* __restrict__ in,
                                           ushort4* __restrict__ out, int n4) {
  int stride = gridDim.x * blockDim.x;
  for (int i = blockIdx.x * blockDim.x + threadIdx.x; i < n4; i += stride) {
    float4 f = in[i];
    ushort4 o;
    o.x = f2bf(f.x); o.y = f2bf(f.y); o.z = f2bf(f.z); o.w = f2bf(f.w);
    out[i] = o;
  }
}

// W [1024][1024] fp32 -> WT [1024][1024] bf16 transposed (WT[n][d] = W[d][n])
__global__ __launch_bounds__(256) void wtrans(const float* __restrict__ W,
                                              u16* __restrict__ WT) {
  __shared__ float tile[32][33];
  const int tx = threadIdx.x, ty = threadIdx.y;  // 32 x 8
  const int d0 = blockIdx.y * 32, n0 = blockIdx.x * 32;
#pragma unroll
  for (int i = 0; i < 4; ++i)
    tile[ty + 8 * i][tx] = W[(size_t)(d0 + ty + 8 * i) * 1024 + n0 + tx];
  __syncthreads();
#pragma unroll
  for (int i = 0; i < 4; ++i)
    WT[(size_t)(n0 + ty + 8 * i) * 1024 + d0 + tx] = f2bf(tile[tx][ty + 8 * i]);
}

// C = A * B^T, A [M][K] (row stride lda), B [N][K] (row stride ldb), bf16.
// 128x128 tile, BK=32, 4 waves (2x2), 16x16x32 MFMA, 2-phase LDS double-buffer.
// MODE 0: bf16 out row-major + bias          (q,k projection)
// MODE 1: bf16 out transposed vT[b][n][s]+b  (v projection)
// MODE 2: bf16 out row-major, * 1/32         (scores)
// MODE 3: fp32 out row-major                 (PV -> d_out)
template <int MODE>
__global__ __launch_bounds__(256) void gemm_bt(
    const u16* __restrict__ A, const u16* __restrict__ B,
    const float* __restrict__ bias, void* __restrict__ C,
    int K, int lda, int ldb, int ldc,
    size_t Az, size_t Bz, size_t Cz) {
  __shared__ __attribute__((aligned(16))) u16 lsA[2 * BMBK];
  __shared__ __attribute__((aligned(16))) u16 lsB[2 * BMBK];
  const int tid = threadIdx.x;
  const int lane = tid & 63;
  const int w = tid >> 6;
  const int wr = w >> 1, wc = w & 1;

  // T1: bijective XCD-aware remap of the (x,y) grid (nwg % 8 == 0 for all uses)
  int flat = blockIdx.x + gridDim.x * blockIdx.y;
  const int nwg = gridDim.x * gridDim.y;
  const int cpx = nwg >> 3;
  flat = (flat & 7) * cpx + (flat >> 3);
  const int bm = flat % gridDim.x;
  const int bn = flat / gridDim.x;
  const int z = blockIdx.z;

  A += (size_t)z * Az;
  B += (size_t)z * Bz;

  // staging: wave w stages rows [w*32, w*32+32); one issue = 16 rows (4 lanes/row).
  const int srow = lane >> 2;
  const int scol = (lane & 3) * 8;
  const u16* Ag0 = A + (size_t)(bm * BM + w * 32 + srow) * lda + scol;
  const u16* Ag1 = Ag0 + (size_t)16 * lda;
  const u16* Bg0 = B + (size_t)(bn * BN + w * 32 + srow) * ldb + scol;
  const u16* Bg1 = Bg0 + (size_t)16 * ldb;
  u16* lA0 = &lsA[(w * 32) * BK];
  u16* lA1 = &lsA[(w * 32 + 16) * BK];
  u16* lB0 = &lsB[(w * 32) * BK];
  u16* lB1 = &lsB[(w * 32 + 16) * BK];

  const int arow = wr * 64 + (lane & 15);  // + m*16
  const int brow = wc * 64 + (lane & 15);  // + n*16
  const int ko = (lane >> 4) * 8;          // k-offset of this lane's 8 elems

  f32x4 acc[4][4] = {};

  auto compute = [&](int cur) {
    const u16* sA = lsA + cur * BMBK;
    const u16* sB = lsB + cur * BMBK;
    short8 af[4], bfr[4];
#pragma unroll
    for (int m = 0; m < 4; ++m)
      af[m] = *(const short8*)&sA[(arow + m * 16) * BK + ko];
#pragma unroll
    for (int n = 0; n < 4; ++n)
      bfr[n] = *(const short8*)&sB[(brow + n * 16) * BK + ko];
#pragma unroll
    for (int m = 0; m < 4; ++m)
#pragma unroll
      for (int n = 0; n < 4; ++n)
        acc[m][n] =
            __builtin_amdgcn_mfma_f32_16x16x32_bf16(af[m], bfr[n], acc[m][n], 0, 0, 0);
  };

  // prologue: stage K-tile 0 into buf 0
  stage16(Ag0, lA0);
  stage16(Ag1, lA1);
  stage16(Bg0, lB0);
  stage16(Bg1, lB1);
  __syncthreads();  // vmcnt(0) + barrier

  int cur = 0;
  int k0 = 0;
  for (; k0 + BK < K; k0 += BK) {
    const int off = (cur ^ 1) * BMBK;
    const int kn = k0 + BK;
    stage16(Ag0 + kn, lA0 + off);  // issue next tile first (overlaps compute)
    stage16(Ag1 + kn, lA1 + off);
    stage16(Bg0 + kn, lB0 + off);
    stage16(Bg1 + kn, lB1 + off);
    compute(cur);
    __syncthreads();  // drains vmcnt -> next buf ready; protects buf reuse
    cur ^= 1;
  }
  compute(cur);  // last tile, no prefetch

  // D layout: col = lane&15, row = (lane>>4)*4 + j
  const int col0 = bn * BN + wc * 64 + (lane & 15);
  const int row0 = bm * BM + wr * 64 + ((lane >> 4) << 2);

  if constexpr (MODE == 0) {
    u16* Cb = (u16*)C;
#pragma unroll
    for (int m = 0; m < 4; ++m)
#pragma unroll
      for (int n = 0; n < 4; ++n) {
        const int c = col0 + n * 16;
        const float bv = bias[c];
#pragma unroll
        for (int j = 0; j < 4; ++j)
          Cb[(size_t)(row0 + m * 16 + j) * ldc + c] = f2bf(acc[m][n][j] + bv);
      }
  } else if constexpr (MODE == 1) {
    u16* Cb = (u16*)C;  // vT [8][1024][2048]
#pragma unroll
    for (int m = 0; m < 4; ++m) {
      const int s0 = row0 + m * 16;
      const int b = s0 >> 11;
      const int s = s0 & 2047;
#pragma unroll
      for (int n = 0; n < 4; ++n) {
        const int c = col0 + n * 16;
        const float bv = bias[c];
        ushort4 o;
        o.x = f2bf(acc[m][n][0] + bv);
        o.y = f2bf(acc[m][n][1] + bv);
        o.z = f2bf(acc[m][n][2] + bv);
        o.w = f2bf(acc[m][n][3] + bv);
        *(ushort4*)&Cb[((size_t)b * 1024 + c) * 2048 + s] = o;
      }
    }
  } else if constexpr (MODE == 2) {
    u16* Cb = (u16*)C + (size_t)z * Cz;
#pragma unroll
    for (int m = 0; m < 4; ++m)
#pragma unroll
      for (int n = 0; n < 4; ++n) {
        const int c = col0 + n * 16;
#pragma unroll
        for (int j = 0; j < 4; ++j)
          Cb[(size_t)(row0 + m * 16 + j) * ldc + c] = f2bf(acc[m][n][j] * 0.03125f);
      }
  } else {
    float* Cb = (float*)C + (size_t)z * Cz;
#pragma unroll
    for (int m = 0; m < 4; ++m)
#pragma unroll
      for (int n = 0; n < 4; ++n) {
        const int c = col0 + n * 16;
#pragma unroll
        for (int j = 0; j < 4; ++j)
          Cb[(size_t)(row0 + m * 16 + j) * ldc + c] = acc[m][n][j];
      }
  }
}

// Masked row softmax over bf16 scores [2048]; writes P bf16 in place.
// mask[row]==0 -> uniform 1/2048 (ref: all scores -> exactly -1e9 in fp32).
__global__ __launch_bounds__(256) void softmax_mask(u16* __restrict__ scores,
                                                    const int* __restrict__ mask) {
  const int row = blockIdx.x, b = blockIdx.y;
  const int t = threadIdx.x, lane = t & 63, w = t >> 6;
  u16* sc = scores + ((size_t)(b * 2048 + row) << 11);
  const int mrow = mask[b * 2048 + row];
  if (mrow == 0) {
    const u16 pv = f2bf(1.0f / 2048.0f);
    ushort4 o;
    o.x = o.y = o.z = o.w = pv;
    *(ushort4*)&sc[t * 8] = o;
    *(ushort4*)&sc[t * 8 + 4] = o;
    return;
  }
  const ushort4 h0 = ((const ushort4*)sc)[t * 2];
  const ushort4 h1 = ((const ushort4*)sc)[t * 2 + 1];
  const int4 m0 = ((const int4*)(mask + b * 2048))[t * 2];
  const int4 m1 = ((const int4*)(mask + b * 2048))[t * 2 + 1];
  float v[8] = {bf2f(h0.x), bf2f(h0.y), bf2f(h0.z), bf2f(h0.w),
                bf2f(h1.x), bf2f(h1.y), bf2f(h1.z), bf2f(h1.w)};
  const int mm[8] = {m0.x, m0.y, m0.z, m0.w, m1.x, m1.y, m1.z, m1.w};
  float lmax = -3.0e38f;
#pragma unroll
  for (int i = 0; i < 8; ++i)
    if (mm[i]) lmax = fmaxf(lmax, v[i]);
#pragma unroll
  for (int off = 32; off >= 1; off >>= 1) lmax = fmaxf(lmax, __shfl_xor(lmax, off));
  __shared__ float red[8];
  if (lane == 0) red[w] = lmax;
  __syncthreads();
  const float bmax = fmaxf(fmaxf(red[0], red[1]), fmaxf(red[2], red[3]));
  float e[8];
  float lsum = 0.f;
#pragma unroll
  for (int i = 0; i < 8; ++i) {
    e[i] = mm[i] ? __expf(v[i] - bmax) : 0.f;
    lsum += e[i];
  }
#pragma unroll
  for (int off = 32; off >= 1; off >>= 1) lsum += __shfl_xor(lsum, off);
  if (lane == 0) red[4 + w] = lsum;
  __syncthreads();
  const float inv = 1.0f / ((red[4] + red[5]) + (red[6] + red[7]));
  ushort4 o0, o1;
  o0.x = f2bf(e[0] * inv); o0.y = f2bf(e[1] * inv);
  o0.z = f2bf(e[2] * inv); o0.w = f2bf(e[3] * inv);
  o1.x = f2bf(e[4] * inv); o1.y = f2bf(e[5] * inv);
  o1.z = f2bf(e[6] * inv); o1.w = f2bf(e[7] * inv);
  *(ushort4*)&sc[t * 8] = o0;
  *(ushort4*)&sc[t * 8 + 4] = o1;
}

extern "C" void kernel_launch(void* const* d_in, const int* in_sizes, int n_in,
                              void* d_out, int out_size, void* d_ws, size_t ws_size,
                              hipStream_t stream) {
  const float* in_q = (const float*)d_in[0];
  const float* in_k = (const float*)d_in[1];
  const float* in_v = (const float*)d_in[2];
  const int* mask = (const int*)d_in[3];
  const float* Wq = (const float*)d_in[4];
  const float* bq = (const float*)d_in[5];
  const float* Wk = (const float*)d_in[6];
  const float* bk = (const float*)d_in[7];
  const float* Wv = (const float*)d_in[8];
  const float* bv = (const float*)d_in[9];

  char* ws = (char*)d_ws;
  const size_t SZ = (size_t)16384 * 1024 * 2;  // 32M bytes
  u16* qb = (u16*)(ws);
  u16* kb = (u16*)(ws + SZ);
  u16* vT = (u16*)(ws + 2 * SZ);
  u16* Aq = (u16*)(ws + 3 * SZ);
  u16* Ak = (u16*)(ws + 4 * SZ);
  u16* Av = (u16*)(ws + 5 * SZ);
  u16* WqT = (u16*)(ws + 6 * SZ);
  u16* WkT = WqT + 1024 * 1024;
  u16* WvT = WkT + 1024 * 1024;
  u16* scores = (u16*)(ws + 3 * SZ);  // bf16 [8][2048][2048], overlays A region

  // 1) converts
  const int n4 = 16384 * 1024 / 4;
  cvt<<<2048, 256, 0, stream>>>((const float4*)in_q, (ushort4*)Aq, n4);
  cvt<<<2048, 256, 0, stream>>>((const float4*)in_k, (ushort4*)Ak, n4);
  cvt<<<2048, 256, 0, stream>>>((const float4*)in_v, (ushort4*)Av, n4);
  dim3 wtb(32, 8);
  wtrans<<<dim3(32, 32), wtb, 0, stream>>>(Wq, WqT);
  wtrans<<<dim3(32, 32), wtb, 0, stream>>>(Wk, WkT);
  wtrans<<<dim3(32, 32), wtb, 0, stream>>>(Wv, WvT);

  // 2) projections
  gemm_bt<0><<<dim3(128, 8, 1), 256, 0, stream>>>(Aq, WqT, bq, qb, 1024, 1024, 1024,
                                                  1024, 0, 0, 0);
  gemm_bt<0><<<dim3(128, 8, 1), 256, 0, stream>>>(Ak, WkT, bk, kb, 1024, 1024, 1024,
                                                  1024, 0, 0, 0);
  gemm_bt<1><<<dim3(128, 8, 1), 256, 0, stream>>>(Av, WvT, bv, vT, 1024, 1024, 1024,
                                                  2048, 0, 0, 0);

  // 3) scores[b] = q[b] k[b]^T / 32  (bf16 out)
  gemm_bt<2><<<dim3(16, 16, 8), 256, 0, stream>>>(
      qb, kb, nullptr, scores, 1024, 1024, 1024, 2048,
      (size_t)2048 * 1024, (size_t)2048 * 1024, (size_t)2048 * 2048);

  // 4) masked softmax -> P bf16 in place
  softmax_mask<<<dim3(2048, 8), 256, 0, stream>>>(scores, mask);

  // 5) out[b] = P[b] vT[b]^T
  gemm_bt<3><<<dim3(16, 8, 8), 256, 0, stream>>>(
      scores, vT, nullptr, d_out, 2048, 2048, 2048, 1024,
      (size_t)2048 * 2048, (size_t)1024 * 2048, (size_t)2048 * 1024);
}

// Round 3
// 373.522 us; speedup vs baseline: 1.2281x; 1.2281x over previous
//
#include <hip/hip_runtime.h>
#include <stdint.h>

// SelfAttentionV3: out = softmax(mask(QK^T/32)) V, Q=Xq Wq+bq etc.
// B=8, S=2048, D=1024. GEMMs: bf16 MFMA, 256x128 tile, BK=64, 3-slot LDS
// pipeline with counted vmcnt(6) (T3+T4), XOR-swizzled LDS (T2), setprio (T5).
//
// ws layout (bytes):
//   [0,    32M)  q_bf16  [16384][1024]
//   [32M,  64M)  k_bf16  [16384][1024]
//   [64M,  96M)  vT_bf16 [8][1024][2048]
//   [96M, 192M)  A_bf16 converted inputs (dead after projections)
//   [192M,198M)  WT_bf16 transposed weights (dead after projections)
//   [96M, 163M)  scores/P bf16 [8][2048][2048] (overlays A region)

typedef unsigned short u16;
typedef __attribute__((ext_vector_type(8))) short short8;
typedef __attribute__((ext_vector_type(4))) float f32x4;

#define BM 256
#define BN 128
#define BK 64
#define SLOT_BYTES 49152   // A: 256*64*2 = 32768, B: 128*64*2 = 16384
#define A_BYTES 32768

__device__ __forceinline__ u16 f2bf(float x) {
  unsigned u = __float_as_uint(x);
  return (u16)((u + 0x7FFFu + ((u >> 16) & 1u)) >> 16);  // RNE
}
__device__ __forceinline__ float bf2f(u16 h) {
  return __uint_as_float(((unsigned)h) << 16);
}

__device__ __forceinline__ void stage16(const void* g, void* l) {
  const __attribute__((address_space(1))) uint32_t* gp =
      (const __attribute__((address_space(1))) uint32_t*)(uintptr_t)g;
  __attribute__((address_space(3))) uint32_t* lp =
      (__attribute__((address_space(3))) uint32_t*)(uintptr_t)l;
  __builtin_amdgcn_global_load_lds(gp, lp, 16, 0, 0);
}

// fp32 -> bf16 elementwise convert
__global__ __launch_bounds__(256) void cvt(const float4* __restrict__ in,
                                           ushort4* __restrict__ out, int n4) {
  int stride = gridDim.x * blockDim.x;
  for (int i = blockIdx.x * blockDim.x + threadIdx.x; i < n4; i += stride) {
    float4 f = in[i];
    ushort4 o;
    o.x = f2bf(f.x); o.y = f2bf(f.y); o.z = f2bf(f.z); o.w = f2bf(f.w);
    out[i] = o;
  }
}

// W [1024][1024] fp32 -> WT bf16 transposed
__global__ __launch_bounds__(256) void wtrans(const float* __restrict__ W,
                                              u16* __restrict__ WT) {
  __shared__ float tile[32][33];
  const int tx = threadIdx.x, ty = threadIdx.y;  // 32 x 8
  const int d0 = blockIdx.y * 32, n0 = blockIdx.x * 32;
#pragma unroll
  for (int i = 0; i < 4; ++i)
    tile[ty + 8 * i][tx] = W[(size_t)(d0 + ty + 8 * i) * 1024 + n0 + tx];
  __syncthreads();
#pragma unroll
  for (int i = 0; i < 4; ++i)
    WT[(size_t)(n0 + ty + 8 * i) * 1024 + d0 + tx] = f2bf(tile[tx][ty + 8 * i]);
}

// C = A * B^T. A [M][K] bf16 (row stride lda), B [N][K] bf16 (row stride ldb).
// 256x128 tile, BK=64, 512 threads = 8 waves (4 wr x 2 wc), wave tile 64x64.
// 3 LDS slots; tile u+2 staged during iter u; vmcnt(6)+barrier per K-tile.
// MODE 0: bf16 out + bias; MODE 1: bf16 out transposed vT + bias;
// MODE 2: bf16 out * 1/32; MODE 3: fp32 out.
template <int MODE>
__global__ __launch_bounds__(512, 2) void gemm256(
    const u16* __restrict__ A, const u16* __restrict__ B,
    const float* __restrict__ bias, void* __restrict__ C,
    int K, int lda, int ldb, int ldc, int nbn,
    size_t Az, size_t Bz, size_t Cz) {
  __shared__ __attribute__((aligned(16))) char smem_[3 * SLOT_BYTES];
  const int tid = threadIdx.x;
  const int lane = tid & 63;
  const int w = tid >> 6;      // 0..7
  const int wr = w >> 1;       // 0..3
  const int wc = w & 1;        // 0..1

  // XCD-aware bijective remap, bn-fastest within chunk (nwg % 8 == 0).
  const int nwg = gridDim.x;
  const int cpx = nwg >> 3;
  int flat = blockIdx.x;
  flat = (flat & 7) * cpx + (flat >> 3);
  const int bn = flat % nbn;
  const int bm = flat / nbn;
  const int z = blockIdx.y;

  A += (size_t)z * Az;
  B += (size_t)z * Bz;

  // ---- staging addressing (linear LDS dest, inverse-swizzled global src) ----
  // issue covers 64 rows: thread t -> row w*8 + (lane>>3), phys col (lane&7)*16B.
  // logical col = phys ^ ((row&7)<<4) bytes -> elems:
  const int srow = w * 8 + (lane >> 3);                       // 0..63
  const int scol = (((lane & 7) ^ ((lane >> 3) & 7)) << 3);   // elems
  const u16* Abase = A + (size_t)(bm * BM + srow) * lda + scol;
  const u16* Bbase = B + (size_t)(bn * BN + srow) * ldb + scol;
  char* ldst = smem_ + w * 1024;  // wave-uniform base; HW adds lane*16

  // ---- fragment read addressing (swizzled) ----
  const int fr = lane & 15;          // frag row
  const int fq = lane >> 4;          // 0..3
  const int fxor = (fr & 7) << 4;    // per-lane swizzle term
  const int aRowB = (wr * 64 + fr) * 128;
  const int bRowB = (wc * 64 + fr) * 128;

  f32x4 acc[4][4] = {};

  auto stage = [&](int kt, int slot) {
    const u16* Ag = Abase + (size_t)kt * BK;
    const u16* Bg = Bbase + (size_t)kt * BK;
    char* sl = ldst + slot * SLOT_BYTES;
#pragma unroll
    for (int i = 0; i < 4; ++i)
      stage16(Ag + (size_t)(i * 64) * lda, sl + i * 8192);
#pragma unroll
    for (int i = 0; i < 2; ++i)
      stage16(Bg + (size_t)(i * 64) * ldb, sl + A_BYTES + i * 8192);
  };

  auto compute = [&](int slot) {
    const char* sA = smem_ + slot * SLOT_BYTES;
    const char* sB = sA + A_BYTES;
#pragma unroll
    for (int ks = 0; ks < 2; ++ks) {
      const int kx = (ks * 64 + fq * 16) ^ fxor;
      short8 a[4], b[4];
#pragma unroll
      for (int m = 0; m < 4; ++m)
        a[m] = *(const short8*)(sA + aRowB + m * 2048 + kx);
#pragma unroll
      for (int n = 0; n < 4; ++n)
        b[n] = *(const short8*)(sB + bRowB + n * 2048 + kx);
      __builtin_amdgcn_s_setprio(1);
#pragma unroll
      for (int m = 0; m < 4; ++m)
#pragma unroll
        for (int n = 0; n < 4; ++n)
          acc[m][n] = __builtin_amdgcn_mfma_f32_16x16x32_bf16(a[m], b[n],
                                                              acc[m][n], 0, 0, 0);
      __builtin_amdgcn_s_setprio(0);
    }
  };

  const int NT = K >> 6;  // K/64, >= 16 in all uses

  // prologue: tiles 0,1 into slots 0,1 (6 loads each per wave)
  stage(0, 0);
  stage(1, 1);

  int s0 = 0, s1 = 1, s2 = 2;
  for (int u = 0; u < NT - 1; ++u) {
    asm volatile("s_waitcnt vmcnt(6)" ::: "memory");  // tile u landed; 3 ht in flight
    __builtin_amdgcn_s_barrier();
    if (u + 2 < NT) stage(u + 2, s2);  // slot s2's old tile (u-1) retired above
    compute(s0);
    int t = s0; s0 = s1; s1 = s2; s2 = t;
  }
  asm volatile("s_waitcnt vmcnt(0)" ::: "memory");  // drain last tile
  __builtin_amdgcn_s_barrier();
  compute(s0);

  // D layout: col = lane&15 (B-row), row = (lane>>4)*4 + j (A-row)
  const int col0 = bn * BN + wc * 64 + fr;
  const int row0 = bm * BM + wr * 64 + fq * 4;

  if constexpr (MODE == 0) {
    u16* Cb = (u16*)C;
#pragma unroll
    for (int m = 0; m < 4; ++m)
#pragma unroll
      for (int n = 0; n < 4; ++n) {
        const int c = col0 + n * 16;
        const float bv = bias[c];
#pragma unroll
        for (int j = 0; j < 4; ++j)
          Cb[(size_t)(row0 + m * 16 + j) * ldc + c] = f2bf(acc[m][n][j] + bv);
      }
  } else if constexpr (MODE == 1) {
    u16* Cb = (u16*)C;  // vT [8][1024][2048]
#pragma unroll
    for (int m = 0; m < 4; ++m) {
      const int s0r = row0 + m * 16;
      const int b = s0r >> 11;
      const int s = s0r & 2047;
#pragma unroll
      for (int n = 0; n < 4; ++n) {
        const int c = col0 + n * 16;
        const float bv = bias[c];
        ushort4 o;
        o.x = f2bf(acc[m][n][0] + bv);
        o.y = f2bf(acc[m][n][1] + bv);
        o.z = f2bf(acc[m][n][2] + bv);
        o.w = f2bf(acc[m][n][3] + bv);
        *(ushort4*)&Cb[((size_t)b * 1024 + c) * 2048 + s] = o;
      }
    }
  } else if constexpr (MODE == 2) {
    u16* Cb = (u16*)C + (size_t)z * Cz;
#pragma unroll
    for (int m = 0; m < 4; ++m)
#pragma unroll
      for (int n = 0; n < 4; ++n) {
        const int c = col0 + n * 16;
#pragma unroll
        for (int j = 0; j < 4; ++j)
          Cb[(size_t)(row0 + m * 16 + j) * ldc + c] = f2bf(acc[m][n][j] * 0.03125f);
      }
  } else {
    float* Cb = (float*)C + (size_t)z * Cz;
#pragma unroll
    for (int m = 0; m < 4; ++m)
#pragma unroll
      for (int n = 0; n < 4; ++n) {
        const int c = col0 + n * 16;
#pragma unroll
        for (int j = 0; j < 4; ++j)
          Cb[(size_t)(row0 + m * 16 + j) * ldc + c] = acc[m][n][j];
      }
  }
}

// Masked row softmax over bf16 scores [2048]; writes P bf16 in place.
__global__ __launch_bounds__(256) void softmax_mask(u16* __restrict__ scores,
                                                    const int* __restrict__ mask) {
  const int row = blockIdx.x, b = blockIdx.y;
  const int t = threadIdx.x, lane = t & 63, w = t >> 6;
  u16* sc = scores + ((size_t)(b * 2048 + row) << 11);
  const int mrow = mask[b * 2048 + row];
  if (mrow == 0) {
    const u16 pv = f2bf(1.0f / 2048.0f);
    ushort4 o;
    o.x = o.y = o.z = o.w = pv;
    *(ushort4*)&sc[t * 8] = o;
    *(ushort4*)&sc[t * 8 + 4] = o;
    return;
  }
  const ushort4 h0 = ((const ushort4*)sc)[t * 2];
  const ushort4 h1 = ((const ushort4*)sc)[t * 2 + 1];
  const int4 m0 = ((const int4*)(mask + b * 2048))[t * 2];
  const int4 m1 = ((const int4*)(mask + b * 2048))[t * 2 + 1];
  float v[8] = {bf2f(h0.x), bf2f(h0.y), bf2f(h0.z), bf2f(h0.w),
                bf2f(h1.x), bf2f(h1.y), bf2f(h1.z), bf2f(h1.w)};
  const int mm[8] = {m0.x, m0.y, m0.z, m0.w, m1.x, m1.y, m1.z, m1.w};
  float lmax = -3.0e38f;
#pragma unroll
  for (int i = 0; i < 8; ++i)
    if (mm[i]) lmax = fmaxf(lmax, v[i]);
#pragma unroll
  for (int off = 32; off >= 1; off >>= 1) lmax = fmaxf(lmax, __shfl_xor(lmax, off));
  __shared__ float red[8];
  if (lane == 0) red[w] = lmax;
  __syncthreads();
  const float bmax = fmaxf(fmaxf(red[0], red[1]), fmaxf(red[2], red[3]));
  float e[8];
  float lsum = 0.f;
#pragma unroll
  for (int i = 0; i < 8; ++i) {
    e[i] = mm[i] ? __expf(v[i] - bmax) : 0.f;
    lsum += e[i];
  }
#pragma unroll
  for (int off = 32; off >= 1; off >>= 1) lsum += __shfl_xor(lsum, off);
  if (lane == 0) red[4 + w] = lsum;
  __syncthreads();
  const float inv = 1.0f / ((red[4] + red[5]) + (red[6] + red[7]));
  ushort4 o0, o1;
  o0.x = f2bf(e[0] * inv); o0.y = f2bf(e[1] * inv);
  o0.z = f2bf(e[2] * inv); o0.w = f2bf(e[3] * inv);
  o1.x = f2bf(e[4] * inv); o1.y = f2bf(e[5] * inv);
  o1.z = f2bf(e[6] * inv); o1.w = f2bf(e[7] * inv);
  *(ushort4*)&sc[t * 8] = o0;
  *(ushort4*)&sc[t * 8 + 4] = o1;
}

extern "C" void kernel_launch(void* const* d_in, const int* in_sizes, int n_in,
                              void* d_out, int out_size, void* d_ws, size_t ws_size,
                              hipStream_t stream) {
  const float* in_q = (const float*)d_in[0];
  const float* in_k = (const float*)d_in[1];
  const float* in_v = (const float*)d_in[2];
  const int* mask = (const int*)d_in[3];
  const float* Wq = (const float*)d_in[4];
  const float* bq = (const float*)d_in[5];
  const float* Wk = (const float*)d_in[6];
  const float* bk = (const float*)d_in[7];
  const float* Wv = (const float*)d_in[8];
  const float* bv = (const float*)d_in[9];

  char* ws = (char*)d_ws;
  const size_t SZ = (size_t)16384 * 1024 * 2;  // 32M bytes
  u16* qb = (u16*)(ws);
  u16* kb = (u16*)(ws + SZ);
  u16* vT = (u16*)(ws + 2 * SZ);
  u16* Aq = (u16*)(ws + 3 * SZ);
  u16* Ak = (u16*)(ws + 4 * SZ);
  u16* Av = (u16*)(ws + 5 * SZ);
  u16* WqT = (u16*)(ws + 6 * SZ);
  u16* WkT = WqT + 1024 * 1024;
  u16* WvT = WkT + 1024 * 1024;
  u16* scores = (u16*)(ws + 3 * SZ);  // bf16 [8][2048][2048], overlays A region

  // 1) converts
  const int n4 = 16384 * 1024 / 4;
  cvt<<<2048, 256, 0, stream>>>((const float4*)in_q, (ushort4*)Aq, n4);
  cvt<<<2048, 256, 0, stream>>>((const float4*)in_k, (ushort4*)Ak, n4);
  cvt<<<2048, 256, 0, stream>>>((const float4*)in_v, (ushort4*)Av, n4);
  dim3 wtb(32, 8);
  wtrans<<<dim3(32, 32), wtb, 0, stream>>>(Wq, WqT);
  wtrans<<<dim3(32, 32), wtb, 0, stream>>>(Wk, WkT);
  wtrans<<<dim3(32, 32), wtb, 0, stream>>>(Wv, WvT);

  // 2) projections: [16384x1024] x [1024x1024]^T ; grid 64 bm x 8 bn = 512
  gemm256<0><<<dim3(512, 1), 512, 0, stream>>>(Aq, WqT, bq, qb, 1024, 1024, 1024,
                                               1024, 8, 0, 0, 0);
  gemm256<0><<<dim3(512, 1), 512, 0, stream>>>(Ak, WkT, bk, kb, 1024, 1024, 1024,
                                               1024, 8, 0, 0, 0);
  gemm256<1><<<dim3(512, 1), 512, 0, stream>>>(Av, WvT, bv, vT, 1024, 1024, 1024,
                                               2048, 8, 0, 0, 0);

  // 3) scores[b] = q[b] k[b]^T / 32 ; per batch 8 bm x 16 bn = 128 blocks
  gemm256<2><<<dim3(128, 8), 512, 0, stream>>>(
      qb, kb, nullptr, scores, 1024, 1024, 1024, 2048, 16,
      (size_t)2048 * 1024, (size_t)2048 * 1024, (size_t)2048 * 2048);

  // 4) masked softmax -> P bf16 in place
  softmax_mask<<<dim3(2048, 8), 256, 0, stream>>>(scores, mask);

  // 5) out[b] = P[b] vT[b]^T ; per batch 8 bm x 8 bn = 64 blocks
  gemm256<3><<<dim3(64, 8), 512, 0, stream>>>(
      scores, vT, nullptr, d_out, 2048, 2048, 2048, 1024, 8,
      (size_t)2048 * 2048, (size_t)1024 * 2048, (size_t)2048 * 1024);
}

// Round 4
// 342.471 us; speedup vs baseline: 1.3395x; 1.0907x over previous
//
#include <hip/hip_runtime.h>
#include <stdint.h>

// SelfAttentionV3: out = softmax(mask(QK^T/32)) V, Q=Xq Wq+bq etc.
// B=8, S=2048, D=1024. GEMMs: bf16 MFMA, 256x256 tile, BK=64, 8-phase
// schedule (T3+T4 counted vmcnt), XOR-swizzled LDS (T2), setprio (T5).
//
// ws layout (bytes):
//   [0,    32M)  q_bf16  [16384][1024]
//   [32M,  64M)  k_bf16  [16384][1024]
//   [64M,  96M)  vT_bf16 [8][1024][2048]
//   [96M, 192M)  A_bf16 converted inputs (dead after projections)
//   [192M,198M)  WT_bf16 transposed weights (dead after projections)
//   [96M, 163M)  scores/P bf16 [8][2048][2048] (overlays A region)

typedef unsigned short u16;
typedef __attribute__((ext_vector_type(8))) short short8;
typedef __attribute__((ext_vector_type(4))) float f32x4;

__device__ __forceinline__ u16 f2bf(float x) {
  unsigned u = __float_as_uint(x);
  return (u16)((u + 0x7FFFu + ((u >> 16) & 1u)) >> 16);  // RNE
}
__device__ __forceinline__ float bf2f(u16 h) {
  return __uint_as_float(((unsigned)h) << 16);
}

__device__ __forceinline__ void stage16(const void* g, void* l) {
  const __attribute__((address_space(1))) uint32_t* gp =
      (const __attribute__((address_space(1))) uint32_t*)(uintptr_t)g;
  __attribute__((address_space(3))) uint32_t* lp =
      (__attribute__((address_space(3))) uint32_t*)(uintptr_t)l;
  __builtin_amdgcn_global_load_lds(gp, lp, 16, 0, 0);
}

__global__ __launch_bounds__(256) void cvt(const float4* __restrict__ in,
                                           ushort4* __restrict__ out, int n4) {
  int stride = gridDim.x * blockDim.x;
  for (int i = blockIdx.x * blockDim.x + threadIdx.x; i < n4; i += stride) {
    float4 f = in[i];
    ushort4 o;
    o.x = f2bf(f.x); o.y = f2bf(f.y); o.z = f2bf(f.z); o.w = f2bf(f.w);
    out[i] = o;
  }
}

__global__ __launch_bounds__(256) void wtrans(const float* __restrict__ W,
                                              u16* __restrict__ WT) {
  __shared__ float tile[32][33];
  const int tx = threadIdx.x, ty = threadIdx.y;  // 32 x 8
  const int d0 = blockIdx.y * 32, n0 = blockIdx.x * 32;
#pragma unroll
  for (int i = 0; i < 4; ++i)
    tile[ty + 8 * i][tx] = W[(size_t)(d0 + ty + 8 * i) * 1024 + n0 + tx];
  __syncthreads();
#pragma unroll
  for (int i = 0; i < 4; ++i)
    WT[(size_t)(n0 + ty + 8 * i) * 1024 + d0 + tx] = f2bf(tile[tx][ty + 8 * i]);
}

// ---- 8-phase 256x256 GEMM: C = A * B^T, both bf16 K-contiguous ----
// 512 thr = 8 waves (2M x 4N), wave tile 128x64, BK=64, 2 K-tile LDS bufs.
// LDS per buf: A 256x64 (32KB) @ +0, B 256x64 (32KB) @ +32768; buf1 @ +65536.
// Swizzle: phys_colByte = logical ^ ((row&7)<<4), both-sides involution.
// MODE 0: bf16 out + bias; MODE 1: bf16 out transposed vT + bias;
// MODE 2: bf16 out * 1/32; MODE 3: fp32 out.

#define BAR __builtin_amdgcn_s_barrier()

#define STAGE_HALF(SRC, LD, KT, LDSOFF)                                  \
  {                                                                      \
    _Pragma("unroll") for (int j_ = 0; j_ < 2; ++j_)                     \
        stage16((SRC) + (size_t)(j_ * 64) * (LD) + (size_t)(KT) * 64,    \
                smem + (LDSOFF) + j_ * 8192 + ldsW);                     \
  }

#define READ_A(BUFOFF, MH)                                               \
  {                                                                      \
    _Pragma("unroll") for (int ks_ = 0; ks_ < 2; ++ks_)                  \
        _Pragma("unroll") for (int mf_ = 0; mf_ < 4; ++mf_)              \
            afr[ks_][mf_] = *(const short8*)(smem + (BUFOFF) +           \
                wr * 16384 + (MH) * 8192 + mf_ * 2048 + fr * 128 +       \
                ((ks_ * 64 + fq * 16) ^ fx));                            \
  }

#define READ_B(DST, BUFOFF, NH)                                          \
  {                                                                      \
    _Pragma("unroll") for (int ks_ = 0; ks_ < 2; ++ks_)                  \
        _Pragma("unroll") for (int nf_ = 0; nf_ < 2; ++nf_)              \
            DST[ks_][nf_] = *(const short8*)(smem + 32768 + (BUFOFF) +   \
                wc * 8192 + (NH) * 4096 + nf_ * 2048 + fr * 128 +        \
                ((ks_ * 64 + fq * 16) ^ fx));                            \
  }

#define MFMA_Q(ACC, NH, BARR)                                            \
  __builtin_amdgcn_s_setprio(1);                                         \
  {                                                                      \
    _Pragma("unroll") for (int ks_ = 0; ks_ < 2; ++ks_)                  \
        _Pragma("unroll") for (int mf_ = 0; mf_ < 4; ++mf_)              \
            _Pragma("unroll") for (int nf_ = 0; nf_ < 2; ++nf_)          \
                ACC[mf_][(NH) * 2 + nf_] =                               \
                    __builtin_amdgcn_mfma_f32_16x16x32_bf16(             \
                        afr[ks_][mf_], BARR[ks_][nf_],                   \
                        ACC[mf_][(NH) * 2 + nf_], 0, 0, 0);              \
  }                                                                      \
  __builtin_amdgcn_s_setprio(0);

template <int MODE>
__global__ __launch_bounds__(512, 2) void gemm8p(
    const u16* __restrict__ A, const u16* __restrict__ B,
    const float* __restrict__ bias, void* __restrict__ C,
    int K, int lda, int ldb, int ldc, int nbn,
    size_t Az, size_t Bz, size_t Cz) {
  __shared__ __attribute__((aligned(16))) char smem[131072];
  const int tid = threadIdx.x;
  const int lane = tid & 63;
  const int w = tid >> 6;     // 0..7
  const int wr = w >> 2;      // 0..1 (M)
  const int wc = w & 3;       // 0..3 (N)

  // XCD-aware bijective remap (nwg % 8 == 0 for all grids), bn-fastest.
  const int nwg = gridDim.x;
  const int cpx = nwg >> 3;
  int flat = blockIdx.x;
  flat = (flat & 7) * cpx + (flat >> 3);
  const int bn = flat % nbn;
  const int bm = flat / nbn;
  const int z = blockIdx.y;
  A += (size_t)z * Az;
  B += (size_t)z * Bz;

  // staging: thread covers row w*8 + (lane>>3) (+64*j, +128*h), 16B at
  // phys col (lane&7)*16; global source col inverse-swizzled.
  const int srow = w * 8 + (lane >> 3);
  const int scol = ((lane & 7) ^ (lane >> 3)) << 3;  // elems
  const u16* Asrc = A + (size_t)(bm * 256 + srow) * lda + scol;
  const u16* Bsrc = B + (size_t)(bn * 256 + srow) * ldb + scol;
  const int ldsW = w * 1024;

  // fragment read addressing
  const int fr = lane & 15;
  const int fq = lane >> 4;
  const int fx = (fr & 7) << 4;

  f32x4 acc0[4][4] = {};  // mh=0 rows
  f32x4 acc1[4][4] = {};  // mh=1 rows
  short8 afr[2][4], bf0[2][2], bf1[2][2];

  const int half = K >> 7;  // iterations; 2 K-tiles each

  // prologue: tile0 -> buf0 (these 8 loads first!), tile1 -> buf1
  STAGE_HALF(Bsrc, ldb, 0, 32768);
  STAGE_HALF(Bsrc + (size_t)128 * ldb, ldb, 0, 49152);
  STAGE_HALF(Asrc, lda, 0, 0);
  STAGE_HALF(Asrc + (size_t)128 * lda, lda, 0, 16384);
  STAGE_HALF(Bsrc, ldb, 1, 98304);
  STAGE_HALF(Bsrc + (size_t)128 * ldb, ldb, 1, 114688);
  STAGE_HALF(Asrc, lda, 1, 65536);
  STAGE_HALF(Asrc + (size_t)128 * lda, lda, 1, 81920);
  asm volatile("s_waitcnt vmcnt(8)" ::: "memory");  // tile0 landed
  BAR;

  for (int i = 0; i < half; ++i) {
    const bool st = (i + 1 < half);
    const int kt2 = 2 * i + 2, kt3 = 2 * i + 3;
    // ph1: Q(t0,m0,n0)
    READ_A(0, 0);
    READ_B(bf0, 0, 0);
    BAR; MFMA_Q(acc0, 0, bf0); BAR;
    // ph2: Q(t0,m0,n1)
    READ_B(bf1, 0, 1);
    BAR; MFMA_Q(acc0, 1, bf1); BAR;
    // ph3: Q(t0,m1,n0); B(t0) slots free after ph2 -> restage
    READ_A(0, 1);
    if (st) STAGE_HALF(Bsrc, ldb, kt2, 32768);
    BAR; MFMA_Q(acc1, 0, bf0); BAR;
    // ph4: Q(t0,m1,n1)
    if (st) STAGE_HALF(Bsrc + (size_t)128 * ldb, ldb, kt2, 49152);
    BAR; MFMA_Q(acc1, 1, bf1);
    if (st) { asm volatile("s_waitcnt vmcnt(4)" ::: "memory"); }
    else    { asm volatile("s_waitcnt vmcnt(0)" ::: "memory"); }
    BAR;  // t1 (staged prev iter / prologue) fully landed
    // ph5: Q(t1,m0,n0); A(t0) slots free after ph3 -> restage
    READ_A(65536, 0);
    READ_B(bf0, 65536, 0);
    if (st) STAGE_HALF(Asrc, lda, kt2, 0);
    BAR; MFMA_Q(acc0, 0, bf0); BAR;
    // ph6: Q(t1,m0,n1)
    READ_B(bf1, 65536, 1);
    if (st) STAGE_HALF(Asrc + (size_t)128 * lda, lda, kt2, 16384);
    BAR; MFMA_Q(acc0, 1, bf1); BAR;
    // ph7: Q(t1,m1,n0); B(t1) slots free after ph6
    READ_A(65536, 1);
    if (st) {
      STAGE_HALF(Bsrc, ldb, kt3, 98304);
      STAGE_HALF(Bsrc + (size_t)128 * ldb, ldb, kt3, 114688);
    }
    BAR; MFMA_Q(acc1, 0, bf0); BAR;
    // ph8: Q(t1,m1,n1); A(t1) slots free after ph7
    if (st) {
      STAGE_HALF(Asrc, lda, kt3, 65536);
      STAGE_HALF(Asrc + (size_t)128 * lda, lda, kt3, 81920);
    }
    BAR; MFMA_Q(acc1, 1, bf1);
    asm volatile("s_waitcnt vmcnt(8)" ::: "memory");  // next t0 landed
    BAR;
  }

  // D layout per 16x16 frag: col = fr, row = fq*4 + j.
  const int colb = bn * 256 + wc * 64 + fr;
#pragma unroll
  for (int mh = 0; mh < 2; ++mh) {
    f32x4(&ac)[4][4] = mh ? acc1 : acc0;
    const int rowb = bm * 256 + wr * 128 + mh * 64 + fq * 4;
    if constexpr (MODE == 0) {
      u16* Cb = (u16*)C;
#pragma unroll
      for (int mf = 0; mf < 4; ++mf)
#pragma unroll
        for (int n = 0; n < 4; ++n) {
          const int c = colb + n * 16;
          const float bv = bias[c];
#pragma unroll
          for (int j = 0; j < 4; ++j)
            Cb[(size_t)(rowb + mf * 16 + j) * ldc + c] = f2bf(ac[mf][n][j] + bv);
        }
    } else if constexpr (MODE == 1) {
      u16* Cb = (u16*)C;  // vT [8][1024][2048]
#pragma unroll
      for (int mf = 0; mf < 4; ++mf) {
        const int s0r = rowb + mf * 16;
        const int b_ = s0r >> 11;
        const int s_ = s0r & 2047;
#pragma unroll
        for (int n = 0; n < 4; ++n) {
          const int c = colb + n * 16;
          const float bv = bias[c];
          ushort4 o;
          o.x = f2bf(ac[mf][n][0] + bv);
          o.y = f2bf(ac[mf][n][1] + bv);
          o.z = f2bf(ac[mf][n][2] + bv);
          o.w = f2bf(ac[mf][n][3] + bv);
          *(ushort4*)&Cb[((size_t)b_ * 1024 + c) * 2048 + s_] = o;
        }
      }
    } else if constexpr (MODE == 2) {
      u16* Cb = (u16*)C + (size_t)z * Cz;
#pragma unroll
      for (int mf = 0; mf < 4; ++mf)
#pragma unroll
        for (int n = 0; n < 4; ++n) {
          const int c = colb + n * 16;
#pragma unroll
          for (int j = 0; j < 4; ++j)
            Cb[(size_t)(rowb + mf * 16 + j) * ldc + c] =
                f2bf(ac[mf][n][j] * 0.03125f);
        }
    } else {
      float* Cb = (float*)C + (size_t)z * Cz;
#pragma unroll
      for (int mf = 0; mf < 4; ++mf)
#pragma unroll
        for (int n = 0; n < 4; ++n) {
          const int c = colb + n * 16;
#pragma unroll
          for (int j = 0; j < 4; ++j)
            Cb[(size_t)(rowb + mf * 16 + j) * ldc + c] = ac[mf][n][j];
        }
    }
  }
}

// Masked row softmax over bf16 scores [2048]; writes P bf16 in place.
__global__ __launch_bounds__(256) void softmax_mask(u16* __restrict__ scores,
                                                    const int* __restrict__ mask) {
  const int row = blockIdx.x, b = blockIdx.y;
  const int t = threadIdx.x, lane = t & 63, w = t >> 6;
  u16* sc = scores + ((size_t)(b * 2048 + row) << 11);
  const int mrow = mask[b * 2048 + row];
  if (mrow == 0) {
    const u16 pv = f2bf(1.0f / 2048.0f);
    ushort4 o;
    o.x = o.y = o.z = o.w = pv;
    *(ushort4*)&sc[t * 8] = o;
    *(ushort4*)&sc[t * 8 + 4] = o;
    return;
  }
  const ushort4 h0 = ((const ushort4*)sc)[t * 2];
  const ushort4 h1 = ((const ushort4*)sc)[t * 2 + 1];
  const int4 m0 = ((const int4*)(mask + b * 2048))[t * 2];
  const int4 m1 = ((const int4*)(mask + b * 2048))[t * 2 + 1];
  float v[8] = {bf2f(h0.x), bf2f(h0.y), bf2f(h0.z), bf2f(h0.w),
                bf2f(h1.x), bf2f(h1.y), bf2f(h1.z), bf2f(h1.w)};
  const int mm[8] = {m0.x, m0.y, m0.z, m0.w, m1.x, m1.y, m1.z, m1.w};
  float lmax = -3.0e38f;
#pragma unroll
  for (int i = 0; i < 8; ++i)
    if (mm[i]) lmax = fmaxf(lmax, v[i]);
#pragma unroll
  for (int off = 32; off >= 1; off >>= 1) lmax = fmaxf(lmax, __shfl_xor(lmax, off));
  __shared__ float red[8];
  if (lane == 0) red[w] = lmax;
  __syncthreads();
  const float bmax = fmaxf(fmaxf(red[0], red[1]), fmaxf(red[2], red[3]));
  float e[8];
  float lsum = 0.f;
#pragma unroll
  for (int i = 0; i < 8; ++i) {
    e[i] = mm[i] ? __expf(v[i] - bmax) : 0.f;
    lsum += e[i];
  }
#pragma unroll
  for (int off = 32; off >= 1; off >>= 1) lsum += __shfl_xor(lsum, off);
  if (lane == 0) red[4 + w] = lsum;
  __syncthreads();
  const float inv = 1.0f / ((red[4] + red[5]) + (red[6] + red[7]));
  ushort4 o0, o1;
  o0.x = f2bf(e[0] * inv); o0.y = f2bf(e[1] * inv);
  o0.z = f2bf(e[2] * inv); o0.w = f2bf(e[3] * inv);
  o1.x = f2bf(e[4] * inv); o1.y = f2bf(e[5] * inv);
  o1.z = f2bf(e[6] * inv); o1.w = f2bf(e[7] * inv);
  *(ushort4*)&sc[t * 8] = o0;
  *(ushort4*)&sc[t * 8 + 4] = o1;
}

extern "C" void kernel_launch(void* const* d_in, const int* in_sizes, int n_in,
                              void* d_out, int out_size, void* d_ws, size_t ws_size,
                              hipStream_t stream) {
  const float* in_q = (const float*)d_in[0];
  const float* in_k = (const float*)d_in[1];
  const float* in_v = (const float*)d_in[2];
  const int* mask = (const int*)d_in[3];
  const float* Wq = (const float*)d_in[4];
  const float* bq = (const float*)d_in[5];
  const float* Wk = (const float*)d_in[6];
  const float* bk = (const float*)d_in[7];
  const float* Wv = (const float*)d_in[8];
  const float* bv = (const float*)d_in[9];

  char* ws = (char*)d_ws;
  const size_t SZ = (size_t)16384 * 1024 * 2;  // 32M bytes
  u16* qb = (u16*)(ws);
  u16* kb = (u16*)(ws + SZ);
  u16* vT = (u16*)(ws + 2 * SZ);
  u16* Aq = (u16*)(ws + 3 * SZ);
  u16* Ak = (u16*)(ws + 4 * SZ);
  u16* Av = (u16*)(ws + 5 * SZ);
  u16* WqT = (u16*)(ws + 6 * SZ);
  u16* WkT = WqT + 1024 * 1024;
  u16* WvT = WkT + 1024 * 1024;
  u16* scores = (u16*)(ws + 3 * SZ);  // bf16 [8][2048][2048], overlays A region

  // 1) converts
  const int n4 = 16384 * 1024 / 4;
  cvt<<<2048, 256, 0, stream>>>((const float4*)in_q, (ushort4*)Aq, n4);
  cvt<<<2048, 256, 0, stream>>>((const float4*)in_k, (ushort4*)Ak, n4);
  cvt<<<2048, 256, 0, stream>>>((const float4*)in_v, (ushort4*)Av, n4);
  dim3 wtb(32, 8);
  wtrans<<<dim3(32, 32), wtb, 0, stream>>>(Wq, WqT);
  wtrans<<<dim3(32, 32), wtb, 0, stream>>>(Wk, WkT);
  wtrans<<<dim3(32, 32), wtb, 0, stream>>>(Wv, WvT);

  // 2) projections: 64 bm x 4 bn = 256 blocks
  gemm8p<0><<<dim3(256, 1), 512, 0, stream>>>(Aq, WqT, bq, qb, 1024, 1024, 1024,
                                              1024, 4, 0, 0, 0);
  gemm8p<0><<<dim3(256, 1), 512, 0, stream>>>(Ak, WkT, bk, kb, 1024, 1024, 1024,
                                              1024, 4, 0, 0, 0);
  gemm8p<1><<<dim3(256, 1), 512, 0, stream>>>(Av, WvT, bv, vT, 1024, 1024, 1024,
                                              2048, 4, 0, 0, 0);

  // 3) scores[b] = q[b] k[b]^T / 32 ; per batch 8 bm x 8 bn = 64 blocks
  gemm8p<2><<<dim3(64, 8), 512, 0, stream>>>(
      qb, kb, nullptr, scores, 1024, 1024, 1024, 2048, 8,
      (size_t)2048 * 1024, (size_t)2048 * 1024, (size_t)2048 * 2048);

  // 4) masked softmax -> P bf16 in place
  softmax_mask<<<dim3(2048, 8), 256, 0, stream>>>(scores, mask);

  // 5) out[b] = P[b] vT[b]^T ; per batch 8 bm x 4 bn = 32 blocks
  gemm8p<3><<<dim3(32, 8), 512, 0, stream>>>(
      scores, vT, nullptr, d_out, 2048, 2048, 2048, 1024, 4,
      (size_t)2048 * 2048, (size_t)1024 * 2048, (size_t)2048 * 1024);
}